// Round 4
// baseline (529.301 us; speedup 1.0000x reference)
//
#include <hip/hip_runtime.h>
#include <math.h>

// AlphaBetaFilter: per-(b,c) linear recurrence, single-pass decoupled-lookback scan.
//   pred = L + sl;  g = a*(x - pred);  L' = pred + g;  sl' = sl + b*g
//   s_t = M s_{t-1} + v x_t,  M = [[1-a,1-a],[-ab,1-ab]];  s_0 = (x_0, 0).
// One wave (64 threads, 2 channels each) per chunk of S=64 steps; x chunk kept
// in registers (64 x float2 = 128 VGPR). Aggregate published -> lookback with
// M^S powers (inclusive shortcut) -> replay from register stash.
// Ticket ordering makes the lookback deadlock-free under any dispatch order.
// R4 fix: lookback flag/payload index must use GLOBAL chunk (rowbase + j),
// not local j — R3 read row 0's prefixes for every b>0.

#define B_ 32
#define T_ 4096
#define C_ 128
#define K_ 64
#define S_ (T_ / K_)      // 64
#define C2 (C_ / 2)       // 64 float2 lanes per row
#define NCHUNK (B_ * K_)  // 2048

__device__ __forceinline__ float sig_clamp(float z) {
    float s = 1.0f / (1.0f + expf(-z));
    return fminf(fmaxf(s, 1.0e-4f), 1.0f - 1.0e-4f);
}

#define STEP(xv0, xv1)                                   \
    {                                                    \
        const float p0 = L0 + sl0;                       \
        const float p1 = L1 + sl1;                       \
        const float g0 = a0 * ((xv0) - p0);              \
        const float g1 = a1 * ((xv1) - p1);              \
        L0 = p0 + g0;  sl0 = fmaf(b0, g0, sl0);          \
        L1 = p1 + g1;  sl1 = fmaf(b1, g1, sl1);          \
    }

// flags[0..NCHUNK-1]: 0 = none, 1 = aggregate ready, 2 = inclusive ready.
// flags[NCHUNK] = ticket counter.
__global__ __launch_bounds__(256) void init_flags(int* __restrict__ flags) {
    const int i = blockIdx.x * 256 + threadIdx.x;
    if (i <= NCHUNK) flags[i] = 0;
}

__global__ __launch_bounds__(64, 2) void fused_scan(
        const float* __restrict__ x,
        const float* __restrict__ logit_alpha,
        const float* __restrict__ logit_beta,
        float4* __restrict__ aggW,
        float4* __restrict__ inclS,
        int* __restrict__ flags,
        float* __restrict__ out) {
    const int lane = threadIdx.x;

    // ticket: chunk assignment in start order -> lookback is deadlock-free
    int tk = 0;
    if (lane == 0) tk = atomicAdd(&flags[NCHUNK], 1);
    tk = __shfl(tk, 0);
    const int chunk = tk;
    const int b = chunk >> 6;
    const int k = chunk & (K_ - 1);
    const int rowbase = chunk - k;        // = b * K_ (global index of row's chunk 0)

    const float2 la2 = ((const float2*)logit_alpha)[lane];
    const float2 lb2 = ((const float2*)logit_beta)[lane];
    const float a0 = sig_clamp(la2.x), a1 = sig_clamp(la2.y);
    const float b0 = sig_clamp(lb2.x), b1 = sig_clamp(lb2.y);

    const size_t off = ((size_t)b * T_ + (size_t)k * S_) * C2 + lane;
    const float2* xp = (const float2*)x + off;

    // register stash of the whole x chunk (single HBM read of x)
    float2 xs[S_];
    #pragma unroll
    for (int t = 0; t < S_; ++t) xs[t] = xp[(size_t)t * C2];

    // zero-state run -> aggregate w_k (chunk 0: exact inclusive state)
    float L0, sl0 = 0.0f, L1, sl1 = 0.0f;
    if (k == 0) {
        L0 = xs[0].x; L1 = xs[0].y;
        #pragma unroll
        for (int t = 1; t < S_; ++t) STEP(xs[t].x, xs[t].y);
    } else {
        L0 = 0.0f; L1 = 0.0f;
        #pragma unroll
        for (int t = 0; t < S_; ++t) STEP(xs[t].x, xs[t].y);
    }

    const float4 wk = make_float4(L0, sl0, L1, sl1);
    aggW[(size_t)chunk * 64 + lane] = wk;
    if (k == 0) inclS[(size_t)chunk * 64 + lane] = wk;
    __threadfence();
    if (lane == 0)
        __hip_atomic_store(&flags[chunk], (k == 0) ? 2 : 1,
                           __ATOMIC_RELEASE, __HIP_MEMORY_SCOPE_AGENT);

    float eL0 = 0.0f, es0 = 0.0f, eL1 = 0.0f, es1 = 0.0f;  // exclusive prefix
    if (k > 0) {
        // M^S via 6 squarings (S = 64 = 2^6), per channel
        float m00_0 = 1.0f - a0, m01_0 = 1.0f - a0;
        float m10_0 = -a0 * b0,  m11_0 = 1.0f - a0 * b0;
        float m00_1 = 1.0f - a1, m01_1 = 1.0f - a1;
        float m10_1 = -a1 * b1,  m11_1 = 1.0f - a1 * b1;
        #pragma unroll
        for (int i = 0; i < 6; ++i) {
            float n00 = m00_0 * m00_0 + m01_0 * m10_0;
            float n01 = m00_0 * m01_0 + m01_0 * m11_0;
            float n10 = m10_0 * m00_0 + m11_0 * m10_0;
            float n11 = m10_0 * m01_0 + m11_0 * m11_0;
            m00_0 = n00; m01_0 = n01; m10_0 = n10; m11_0 = n11;
            n00 = m00_1 * m00_1 + m01_1 * m10_1;
            n01 = m00_1 * m01_1 + m01_1 * m11_1;
            n10 = m10_1 * m00_1 + m11_1 * m10_1;
            n11 = m10_1 * m01_1 + m11_1 * m11_1;
            m00_1 = n00; m01_1 = n01; m10_1 = n10; m11_1 = n11;
        }

        // backward lookback; P = (M^S)^(k-1-j) running power
        float p00_0 = 1.0f, p01_0 = 0.0f, p10_0 = 0.0f, p11_0 = 1.0f;
        float p00_1 = 1.0f, p01_1 = 0.0f, p10_1 = 0.0f, p11_1 = 1.0f;
        for (int j = k - 1; j >= 0; --j) {
            const int gj = rowbase + j;      // GLOBAL chunk index of predecessor
            int f = __hip_atomic_load(&flags[gj], __ATOMIC_ACQUIRE,
                                      __HIP_MEMORY_SCOPE_AGENT);
            f = __shfl(f, 0);   // wave-uniform view
            while (f == 0) {
                __builtin_amdgcn_s_sleep(1);
                f = __hip_atomic_load(&flags[gj], __ATOMIC_ACQUIRE,
                                      __HIP_MEMORY_SCOPE_AGENT);
                f = __shfl(f, 0);
            }
            const float4 v = (f == 2 ? inclS : aggW)[(size_t)gj * 64 + lane];
            eL0 += p00_0 * v.x + p01_0 * v.y;
            es0 += p10_0 * v.x + p11_0 * v.y;
            eL1 += p00_1 * v.z + p01_1 * v.w;
            es1 += p10_1 * v.z + p11_1 * v.w;
            if (f == 2) break;   // consumed an inclusive state: done
            {   // P = P * Ms (channel 0)
                const float n00 = p00_0 * m00_0 + p01_0 * m10_0;
                const float n01 = p00_0 * m01_0 + p01_0 * m11_0;
                const float n10 = p10_0 * m00_0 + p11_0 * m10_0;
                const float n11 = p10_0 * m01_0 + p11_0 * m11_0;
                p00_0 = n00; p01_0 = n01; p10_0 = n10; p11_0 = n11;
            }
            {   // P = P * Ms (channel 1)
                const float n00 = p00_1 * m00_1 + p01_1 * m10_1;
                const float n01 = p00_1 * m01_1 + p01_1 * m11_1;
                const float n10 = p10_1 * m00_1 + p11_1 * m10_1;
                const float n11 = p10_1 * m01_1 + p11_1 * m11_1;
                p00_1 = n00; p01_1 = n01; p10_1 = n10; p11_1 = n11;
            }
        }

        // publish inclusive state s_end(k) = Ms * excl + w_k (speeds later walks)
        if (k < K_ - 1) {
            const float iL0 = m00_0 * eL0 + m01_0 * es0 + wk.x;
            const float is0 = m10_0 * eL0 + m11_0 * es0 + wk.y;
            const float iL1 = m00_1 * eL1 + m01_1 * es1 + wk.z;
            const float is1 = m10_1 * eL1 + m11_1 * es1 + wk.w;
            inclS[(size_t)chunk * 64 + lane] = make_float4(iL0, is0, iL1, is1);
            __threadfence();
            if (lane == 0)
                __hip_atomic_store(&flags[chunk], 2,
                                   __ATOMIC_RELEASE, __HIP_MEMORY_SCOPE_AGENT);
        }
    }

    // replay from register stash, emit outputs
    float2* op = (float2*)out + off;
    if (k == 0) {
        L0 = xs[0].x; L1 = xs[0].y; sl0 = 0.0f; sl1 = 0.0f;
        op[0] = make_float2(L0, L1);
        #pragma unroll
        for (int t = 1; t < S_; ++t) {
            STEP(xs[t].x, xs[t].y);
            op[(size_t)t * C2] = make_float2(L0, L1);
        }
    } else {
        L0 = eL0; sl0 = es0; L1 = eL1; sl1 = es1;
        #pragma unroll
        for (int t = 0; t < S_; ++t) {
            STEP(xs[t].x, xs[t].y);
            op[(size_t)t * C2] = make_float2(L0, L1);
        }
    }
}

// Fallback: fully sequential per-(b,c) thread (used only if ws too small).
__global__ void seq_fallback(
        const float* __restrict__ x,
        const float* __restrict__ logit_alpha,
        const float* __restrict__ logit_beta,
        float* __restrict__ out) {
    const int tid = blockIdx.x * blockDim.x + threadIdx.x;
    if (tid >= B_ * C_) return;
    const int b = tid / C_;
    const int c = tid % C_;
    const float a0 = sig_clamp(logit_alpha[c]);
    const float b0 = sig_clamp(logit_beta[c]);
    const float* xp = x + (size_t)b * T_ * C_ + c;
    float* op = out + (size_t)b * T_ * C_ + c;
    float L0 = xp[0], sl0 = 0.0f;
    op[0] = L0;
    for (int t = 1; t < T_; ++t) {
        const float xv = xp[(size_t)t * C_];
        const float p0 = L0 + sl0;
        const float g0 = a0 * (xv - p0);
        L0 = p0 + g0;
        sl0 = fmaf(b0, g0, sl0);
        op[(size_t)t * C_] = L0;
    }
}

extern "C" void kernel_launch(void* const* d_in, const int* in_sizes, int n_in,
                              void* d_out, int out_size, void* d_ws, size_t ws_size,
                              hipStream_t stream) {
    const float* x  = (const float*)d_in[0];
    const float* la = (const float*)d_in[1];
    const float* lb = (const float*)d_in[2];
    float* out = (float*)d_out;

    const size_t n_payload = (size_t)NCHUNK * 64;                 // float4 per array
    const size_t need = 2 * n_payload * sizeof(float4)            // aggW + inclS
                      + (NCHUNK + 1) * sizeof(int);               // flags + ticket

    if (ws_size >= need) {
        float4* aggW  = (float4*)d_ws;
        float4* inclS = aggW + n_payload;
        int* flags    = (int*)(inclS + n_payload);
        init_flags<<<(NCHUNK + 256) / 256, 256, 0, stream>>>(flags);
        fused_scan<<<NCHUNK, 64, 0, stream>>>(x, la, lb, aggW, inclS, flags, out);
    } else {
        seq_fallback<<<(B_ * C_ + 255) / 256, 256, 0, stream>>>(x, la, lb, out);
    }
}

// Round 5
// 314.412 us; speedup vs baseline: 1.6835x; 1.6835x over previous
//
#include <hip/hip_runtime.h>
#include <hip/hip_cooperative_groups.h>
#include <math.h>

namespace cg = cooperative_groups;

// AlphaBetaFilter: per-(b,c) linear recurrence over T steps.
//   pred = L + sl;  g = a*(x - pred);  L' = pred + g;  sl' = sl + b*g
//   s_t = M s_{t-1} + v x_t,  M = [[1-a,1-a],[-ab,1-ab]];  s_0 = (x_0, 0).
// Single cooperative kernel, K=64 chunks of S=64 per batch row:
//   phase A: zero-state run per chunk -> aggregate w_k  (chunk0 = exact state)
//   grid.sync()
//   phase B: per-chunk forward scan of row aggregates with M^S, then replay
//            chunk (x re-read is LLC-warm from phase A) emitting outputs.
// R4 lesson: cross-wave spin-wait lookback is stall-bound on 8-XCD MI355X
// (480 us, VALUBusy 1.2%); bulk pass over L3-resident data wins.

#define B_ 32
#define T_ 4096
#define C_ 128
#define K_ 64
#define S_ (T_ / K_)      // 64
#define C2 (C_ / 2)       // 64 float2 lanes per row
#define NCHUNK (B_ * K_)  // 2048

__device__ __forceinline__ float sig_clamp(float z) {
    float s = 1.0f / (1.0f + expf(-z));
    return fminf(fmaxf(s, 1.0e-4f), 1.0f - 1.0e-4f);
}

#define STEP(xv0, xv1)                                   \
    {                                                    \
        const float p0 = L0 + sl0;                       \
        const float p1 = L1 + sl1;                       \
        const float g0 = a0 * ((xv0) - p0);              \
        const float g1 = a1 * ((xv1) - p1);              \
        L0 = p0 + g0;  sl0 = fmaf(b0, g0, sl0);          \
        L1 = p1 + g1;  sl1 = fmaf(b1, g1, sl1);          \
    }

// 2048 blocks x 64 threads: 8 one-wave blocks/CU, VGPR-capped at 128 -> all
// co-resident under cooperative launch.
__global__ __launch_bounds__(64, 4) void coop_scan(
        const float* __restrict__ x,
        const float* __restrict__ logit_alpha,
        const float* __restrict__ logit_beta,
        float4* __restrict__ aggW,
        float* __restrict__ out) {
    const int lane = threadIdx.x;
    const int chunk = blockIdx.x;
    const int b = chunk >> 6;
    const int k = chunk & (K_ - 1);

    const float2 la2 = ((const float2*)logit_alpha)[lane];
    const float2 lb2 = ((const float2*)logit_beta)[lane];
    const float a0 = sig_clamp(la2.x), a1 = sig_clamp(la2.y);
    const float b0 = sig_clamp(lb2.x), b1 = sig_clamp(lb2.y);

    const size_t off = ((size_t)b * T_ + (size_t)k * S_) * C2 + lane;
    const float2* xp = (const float2*)x + off;

    // ---- phase A: zero-state run -> aggregate (chunk 0: exact state) ----
    float L0, sl0 = 0.0f, L1, sl1 = 0.0f;
    if (k == 0) {
        const float2 v = xp[0];
        L0 = v.x; L1 = v.y;
        #pragma unroll 8
        for (int t = 1; t < S_; ++t) {
            const float2 xv = xp[(size_t)t * C2];
            STEP(xv.x, xv.y);
        }
    } else {
        L0 = 0.0f; L1 = 0.0f;
        #pragma unroll 8
        for (int t = 0; t < S_; ++t) {
            const float2 xv = xp[(size_t)t * C2];
            STEP(xv.x, xv.y);
        }
    }
    aggW[(size_t)chunk * 64 + lane] = make_float4(L0, sl0, L1, sl1);

    __threadfence();          // make aggW visible device-wide before barrier
    cg::this_grid().sync();

    // ---- phase B: prefix scan of row aggregates, then replay chunk ----
    float2* op = (float2*)out + off;
    if (k == 0) {
        const float2 v = xp[0];
        L0 = v.x; L1 = v.y; sl0 = 0.0f; sl1 = 0.0f;
        op[0] = make_float2(L0, L1);
        #pragma unroll 8
        for (int t = 1; t < S_; ++t) {
            const float2 xv = xp[(size_t)t * C2];
            STEP(xv.x, xv.y);
            op[(size_t)t * C2] = make_float2(L0, L1);
        }
    } else {
        // M^S via 6 squarings (S = 64 = 2^6), per channel
        float m00_0 = 1.0f - a0, m01_0 = 1.0f - a0;
        float m10_0 = -a0 * b0,  m11_0 = 1.0f - a0 * b0;
        float m00_1 = 1.0f - a1, m01_1 = 1.0f - a1;
        float m10_1 = -a1 * b1,  m11_1 = 1.0f - a1 * b1;
        #pragma unroll
        for (int i = 0; i < 6; ++i) {
            float n00 = m00_0 * m00_0 + m01_0 * m10_0;
            float n01 = m00_0 * m01_0 + m01_0 * m11_0;
            float n10 = m10_0 * m00_0 + m11_0 * m10_0;
            float n11 = m10_0 * m01_0 + m11_0 * m11_0;
            m00_0 = n00; m01_0 = n01; m10_0 = n10; m11_0 = n11;
            n00 = m00_1 * m00_1 + m01_1 * m10_1;
            n01 = m00_1 * m01_1 + m01_1 * m11_1;
            n10 = m10_1 * m00_1 + m11_1 * m10_1;
            n11 = m10_1 * m01_1 + m11_1 * m11_1;
            m00_1 = n00; m01_1 = n01; m10_1 = n10; m11_1 = n11;
        }
        // forward scan: s = inclusive state through chunk j
        const float4* wp = aggW + (size_t)(chunk - k) * 64 + lane;
        float4 s = wp[0];
        #pragma unroll 4
        for (int j = 1; j < k; ++j) {
            const float4 wj = wp[(size_t)j * 64];
            const float nx = m00_0 * s.x + m01_0 * s.y + wj.x;
            const float ny = m10_0 * s.x + m11_0 * s.y + wj.y;
            const float nz = m00_1 * s.z + m01_1 * s.w + wj.z;
            const float nw = m10_1 * s.z + m11_1 * s.w + wj.w;
            s = make_float4(nx, ny, nz, nw);
        }
        L0 = s.x; sl0 = s.y; L1 = s.z; sl1 = s.w;
        #pragma unroll 8
        for (int t = 0; t < S_; ++t) {
            const float2 xv = xp[(size_t)t * C2];
            STEP(xv.x, xv.y);
            op[(size_t)t * C2] = make_float2(L0, L1);
        }
    }
}

// Fallback: fully sequential per-(b,c) thread (used only if ws too small).
__global__ void seq_fallback(
        const float* __restrict__ x,
        const float* __restrict__ logit_alpha,
        const float* __restrict__ logit_beta,
        float* __restrict__ out) {
    const int tid = blockIdx.x * blockDim.x + threadIdx.x;
    if (tid >= B_ * C_) return;
    const int b = tid / C_;
    const int c = tid % C_;
    const float a0 = sig_clamp(logit_alpha[c]);
    const float b0 = sig_clamp(logit_beta[c]);
    const float* xp = x + (size_t)b * T_ * C_ + c;
    float* op = out + (size_t)b * T_ * C_ + c;
    float L0 = xp[0], sl0 = 0.0f;
    op[0] = L0;
    for (int t = 1; t < T_; ++t) {
        const float xv = xp[(size_t)t * C_];
        const float p0 = L0 + sl0;
        const float g0 = a0 * (xv - p0);
        L0 = p0 + g0;
        sl0 = fmaf(b0, g0, sl0);
        op[(size_t)t * C_] = L0;
    }
}

extern "C" void kernel_launch(void* const* d_in, const int* in_sizes, int n_in,
                              void* d_out, int out_size, void* d_ws, size_t ws_size,
                              hipStream_t stream) {
    const float* x  = (const float*)d_in[0];
    const float* la = (const float*)d_in[1];
    const float* lb = (const float*)d_in[2];
    float* out = (float*)d_out;

    const size_t need = (size_t)NCHUNK * 64 * sizeof(float4);  // aggW = 2 MiB

    if (ws_size >= need) {
        float4* aggW = (float4*)d_ws;
        void* args[] = { (void*)&x, (void*)&la, (void*)&lb,
                         (void*)&aggW, (void*)&out };
        hipLaunchCooperativeKernel((const void*)coop_scan,
                                   dim3(NCHUNK), dim3(64), args, 0, stream);
    } else {
        seq_fallback<<<(B_ * C_ + 255) / 256, 256, 0, stream>>>(x, la, lb, out);
    }
}

// Round 6
// 126.706 us; speedup vs baseline: 4.1774x; 2.4814x over previous
//
#include <hip/hip_runtime.h>
#include <math.h>

// AlphaBetaFilter: per-(b,c) linear recurrence over T steps.
//   pred = L + sl;  g = a*(x - pred);  L' = pred + g;  sl' = sl + b*g
//   s_t = M s_{t-1} + v x_t,  M = [[1-a,1-a],[-ab,1-ab]];  s_0 = (x_0, 0).
// Two-kernel chunked scan (R2 structure — empirically best; in-kernel global
// sync via coop grid.sync (R5: 228us) or spin lookback (R4: 480us) are
// stall-bound on 8-XCD MI355X; separate launches win).
//   p1: per-chunk zero-state run -> aggregate w_k (chunk0 = exact state)
//   p2: per-chunk forward scan of row aggregates with M^S, replay chunk
//       (x re-read is LLC-warm), emit outputs.
// R6: branch-free loops (STEP(x0) from (x0,0) is a no-op), 16-deep explicit
// load batching for ILP (R5 lesson: starved VGPRs -> ~2 outstanding loads),
// nontemporal stores for out / nt loads for p2's single-use x re-read.

#define B_ 32
#define T_ 4096
#define C_ 128
#define K_ 64
#define S_ (T_ / K_)      // 64
#define C2 (C_ / 2)       // 64 float2 lanes per row
#define NCHUNK (B_ * K_)  // 2048
#define BATCH 16

typedef float v2f __attribute__((ext_vector_type(2)));

__device__ __forceinline__ float sig_clamp(float z) {
    float s = 1.0f / (1.0f + expf(-z));
    return fminf(fmaxf(s, 1.0e-4f), 1.0f - 1.0e-4f);
}

#define STEP(xv0, xv1)                                   \
    {                                                    \
        const float p0 = L0 + sl0;                       \
        const float p1 = L1 + sl1;                       \
        const float g0 = a0 * ((xv0) - p0);              \
        const float g1 = a1 * ((xv1) - p1);              \
        L0 = p0 + g0;  sl0 = fmaf(b0, g0, sl0);          \
        L1 = p1 + g1;  sl1 = fmaf(b1, g1, sl1);          \
    }

// Kernel 1: per-chunk aggregates. 4 waves/block, 1 chunk/wave.
__global__ __launch_bounds__(256, 2) void p1_offsets(
        const float* __restrict__ x,
        const float* __restrict__ logit_alpha,
        const float* __restrict__ logit_beta,
        float4* __restrict__ w) {
    const int tid = threadIdx.x & 63;
    const int chunk = blockIdx.x * 4 + (threadIdx.x >> 6);
    const int b = chunk >> 6;
    const int k = chunk & (K_ - 1);

    const float2 la2 = ((const float2*)logit_alpha)[tid];
    const float2 lb2 = ((const float2*)logit_beta)[tid];
    const float a0 = sig_clamp(la2.x), a1 = sig_clamp(la2.y);
    const float b0 = sig_clamp(lb2.x), b1 = sig_clamp(lb2.y);

    const float2* xp = (const float2*)x + ((size_t)b * T_ + (size_t)k * S_) * C2 + tid;

    float2 buf[BATCH];
    float L0, sl0 = 0.0f, L1, sl1 = 0.0f;

    // batch 0 (includes the k==0 init; STEP(x0) from (x0,0) is a no-op)
    #pragma unroll
    for (int i = 0; i < BATCH; ++i) buf[i] = xp[(size_t)i * C2];
    if (k == 0) { L0 = buf[0].x; L1 = buf[0].y; }
    else        { L0 = 0.0f;     L1 = 0.0f;     }
    #pragma unroll
    for (int i = 0; i < BATCH; ++i) STEP(buf[i].x, buf[i].y);

    for (int base = BATCH; base < S_; base += BATCH) {
        #pragma unroll
        for (int i = 0; i < BATCH; ++i) buf[i] = xp[(size_t)(base + i) * C2];
        #pragma unroll
        for (int i = 0; i < BATCH; ++i) STEP(buf[i].x, buf[i].y);
    }

    w[(size_t)chunk * 64 + tid] = make_float4(L0, sl0, L1, sl1);
}

// Kernel 2: scan row aggregates with M^S, replay chunk, emit outputs.
__global__ __launch_bounds__(256, 2) void p2_emit(
        const float* __restrict__ x,
        const float* __restrict__ logit_alpha,
        const float* __restrict__ logit_beta,
        const float4* __restrict__ w,
        float* __restrict__ out) {
    const int tid = threadIdx.x & 63;
    // reverse order: largest-k chunks (most scan work) dispatch first
    const int chunk = (NCHUNK - 1) - (blockIdx.x * 4 + (threadIdx.x >> 6));
    const int b = chunk >> 6;
    const int k = chunk & (K_ - 1);

    const float2 la2 = ((const float2*)logit_alpha)[tid];
    const float2 lb2 = ((const float2*)logit_beta)[tid];
    const float a0 = sig_clamp(la2.x), a1 = sig_clamp(la2.y);
    const float b0 = sig_clamp(lb2.x), b1 = sig_clamp(lb2.y);

    const size_t off = ((size_t)b * T_ + (size_t)k * S_) * C2 + tid;
    const v2f* xp = (const v2f*)x + off;
    v2f* op = (v2f*)out + off;

    float L0, sl0 = 0.0f, L1, sl1 = 0.0f;

    if (k > 0) {
        // M^S via 6 squarings (S = 64 = 2^6), per channel
        float m00_0 = 1.0f - a0, m01_0 = 1.0f - a0;
        float m10_0 = -a0 * b0,  m11_0 = 1.0f - a0 * b0;
        float m00_1 = 1.0f - a1, m01_1 = 1.0f - a1;
        float m10_1 = -a1 * b1,  m11_1 = 1.0f - a1 * b1;
        #pragma unroll
        for (int i = 0; i < 6; ++i) {
            float n00 = m00_0 * m00_0 + m01_0 * m10_0;
            float n01 = m00_0 * m01_0 + m01_0 * m11_0;
            float n10 = m10_0 * m00_0 + m11_0 * m10_0;
            float n11 = m10_0 * m01_0 + m11_0 * m11_0;
            m00_0 = n00; m01_0 = n01; m10_0 = n10; m11_0 = n11;
            n00 = m00_1 * m00_1 + m01_1 * m10_1;
            n01 = m00_1 * m01_1 + m01_1 * m11_1;
            n10 = m10_1 * m00_1 + m11_1 * m10_1;
            n11 = m10_1 * m01_1 + m11_1 * m11_1;
            m00_1 = n00; m01_1 = n01; m10_1 = n10; m11_1 = n11;
        }
        // forward scan of chunks 0..k-1 of this row (w is L2/LLC-resident)
        const float4* wp = w + (size_t)(chunk - k) * 64 + tid;
        float4 s = wp[0];
        #pragma unroll 8
        for (int j = 1; j < k; ++j) {
            const float4 wj = wp[(size_t)j * 64];
            const float nx = m00_0 * s.x + m01_0 * s.y + wj.x;
            const float ny = m10_0 * s.x + m11_0 * s.y + wj.y;
            const float nz = m00_1 * s.z + m01_1 * s.w + wj.z;
            const float nw = m10_1 * s.z + m11_1 * s.w + wj.w;
            s = make_float4(nx, ny, nz, nw);
        }
        L0 = s.x; sl0 = s.y; L1 = s.z; sl1 = s.w;
    }

    v2f buf[BATCH];

    // batch 0 (k==0 init inside; STEP(x0) from (x0,0) is a no-op and out[0]=x0)
    #pragma unroll
    for (int i = 0; i < BATCH; ++i)
        buf[i] = __builtin_nontemporal_load(&xp[(size_t)i * C2]);
    if (k == 0) { L0 = buf[0].x; L1 = buf[0].y; sl0 = 0.0f; sl1 = 0.0f; }
    #pragma unroll
    for (int i = 0; i < BATCH; ++i) {
        STEP(buf[i].x, buf[i].y);
        v2f o; o.x = L0; o.y = L1;
        __builtin_nontemporal_store(o, &op[(size_t)i * C2]);
    }

    for (int base = BATCH; base < S_; base += BATCH) {
        #pragma unroll
        for (int i = 0; i < BATCH; ++i)
            buf[i] = __builtin_nontemporal_load(&xp[(size_t)(base + i) * C2]);
        #pragma unroll
        for (int i = 0; i < BATCH; ++i) {
            STEP(buf[i].x, buf[i].y);
            v2f o; o.x = L0; o.y = L1;
            __builtin_nontemporal_store(o, &op[(size_t)(base + i) * C2]);
        }
    }
}

// Fallback: fully sequential per-(b,c) thread (used only if ws too small).
__global__ void seq_fallback(
        const float* __restrict__ x,
        const float* __restrict__ logit_alpha,
        const float* __restrict__ logit_beta,
        float* __restrict__ out) {
    const int tid = blockIdx.x * blockDim.x + threadIdx.x;
    if (tid >= B_ * C_) return;
    const int b = tid / C_;
    const int c = tid % C_;
    const float a0 = sig_clamp(logit_alpha[c]);
    const float b0 = sig_clamp(logit_beta[c]);
    const float* xp = x + (size_t)b * T_ * C_ + c;
    float* op = out + (size_t)b * T_ * C_ + c;
    float L0 = xp[0], sl0 = 0.0f;
    op[0] = L0;
    for (int t = 1; t < T_; ++t) {
        const float xv = xp[(size_t)t * C_];
        const float p0 = L0 + sl0;
        const float g0 = a0 * (xv - p0);
        L0 = p0 + g0;
        sl0 = fmaf(b0, g0, sl0);
        op[(size_t)t * C_] = L0;
    }
}

extern "C" void kernel_launch(void* const* d_in, const int* in_sizes, int n_in,
                              void* d_out, int out_size, void* d_ws, size_t ws_size,
                              hipStream_t stream) {
    const float* x  = (const float*)d_in[0];
    const float* la = (const float*)d_in[1];
    const float* lb = (const float*)d_in[2];
    float* out = (float*)d_out;

    const size_t need = (size_t)NCHUNK * 64 * sizeof(float4);  // w = 2 MiB

    if (ws_size >= need) {
        float4* w = (float4*)d_ws;
        p1_offsets<<<NCHUNK / 4, 256, 0, stream>>>(x, la, lb, w);
        p2_emit<<<NCHUNK / 4, 256, 0, stream>>>(x, la, lb, w, out);
    } else {
        seq_fallback<<<(B_ * C_ + 255) / 256, 256, 0, stream>>>(x, la, lb, out);
    }
}